// Round 1
// baseline (1231.095 us; speedup 1.0000x reference)
//
#include <hip/hip_runtime.h>
#include <math.h>

#define NPTS   32768
#define CCH    128
#define FMH    480
#define FMW    640
#define PLANE  (FMH*FMW)
#define IMW    640
#define IMH    480
#define TPP    8           // threads per point
#define PPB    32          // points per block
#define NBLK   (NPTS/PPB)  // 1024
#define NPART  27          // 6 (g) + 21 (H upper triangle)

// Per-iteration gather + reduce: writes 27 partial sums per block.
__global__ __launch_bounds__(256)
void pnp_accum(const float* __restrict__ pts3D,
               const float* __restrict__ fref,
               const float* __restrict__ fmap,
               const float* __restrict__ gxm,
               const float* __restrict__ gym,
               const float* __restrict__ Kmat,
               const float* __restrict__ Rsrc,
               const float* __restrict__ tsrc,
               float* __restrict__ partials)
{
    const int tid = threadIdx.x;
    const int g   = tid & (TPP-1);   // channel group 0..7
    const int pl  = tid >> 3;        // point slot in block 0..31
    const int n   = blockIdx.x * PPB + pl;

    const float R00=Rsrc[0],R01=Rsrc[1],R02=Rsrc[2];
    const float R10=Rsrc[3],R11=Rsrc[4],R12=Rsrc[5];
    const float R20=Rsrc[6],R21=Rsrc[7],R22=Rsrc[8];
    const float t0=tsrc[0],t1=tsrc[1],t2=tsrc[2];
    const float K00=Kmat[0],K01=Kmat[1],K02=Kmat[2];
    const float K10=Kmat[3],K11=Kmat[4],K12=Kmat[5];
    const float K20=Kmat[6],K21=Kmat[7],K22=Kmat[8];
    const float fx=K00, fy=K11;

    const float px=pts3D[n*3+0], py=pts3D[n*3+1], pz=pts3D[n*3+2];
    // p3d = pts3D @ R.T + t
    const float x = R00*px + R01*py + R02*pz + t0;
    const float y = R10*px + R11*py + R12*pz + t1;
    const float z = R20*px + R21*py + R22*pz + t2;
    // ph = p3d @ K.T
    const float phx = K00*x + K01*y + K02*z;
    const float phy = K10*x + K11*y + K12*z;
    const float phz = K20*x + K21*y + K22*z;
    // p2d = round(ph.xy/ph.z) - 1   (round half to even, like jnp.round)
    const int p2x = (int)rintf(phx/phz) - 1;
    const int p2y = (int)rintf(phy/phz) - 1;
    const bool inb = (p2x>=0) && (p2y>=0) && (p2x<IMW) && (p2y<IMH);
    // fmH==im_height, fmW==im_width  =>  rows=p2y, cols=p2x for in-bounds pts.

    float sx=0.f, sy=0.f, gxx=0.f, gxy=0.f, gyy=0.f;
    if (inb) {
        const int pix = p2y*FMW + p2x;
        const float* fm = fmap + pix;
        const float* gx = gxm  + pix;
        const float* gy = gym  + pix;
        const float4* refp =
            reinterpret_cast<const float4*>(fref + (size_t)n*CCH + g*16);
        #pragma unroll
        for (int j=0;j<4;j++){
            const float4 rv = refp[j];
            const float rarr[4] = {rv.x, rv.y, rv.z, rv.w};
            const int c0 = g*16 + j*4;
            #pragma unroll
            for (int k=0;k<4;k++){
                const int off = (c0+k)*PLANE;
                const float f = fm[off];
                const float a = gx[off];
                const float b = gy[off];
                const float e = f - rarr[k];
                sx  = fmaf(a,e,sx);
                sy  = fmaf(b,e,sy);
                gxx = fmaf(a,a,gxx);
                gxy = fmaf(a,b,gxy);
                gyy = fmaf(b,b,gyy);
            }
        }
    }
    // reduce the 5 channel-sums across the point's 8 lanes
    #pragma unroll
    for (int d=1; d<TPP; d<<=1){
        sx  += __shfl_xor(sx , d);
        sy  += __shfl_xor(sy , d);
        gxx += __shfl_xor(gxx, d);
        gxy += __shfl_xor(gxy, d);
        gyy += __shfl_xor(gyy, d);
    }

    // per-point contribution to g (6) and H upper-tri (21)
    float v[NPART];
    #pragma unroll
    for (int i=0;i<NPART;i++) v[i]=0.f;
    if (inb) {
        const float zi = 1.f/z;
        const float a0 = fx*zi;
        const float b0 = -fx*x*zi*zi;
        const float c1 = fy*zi;
        const float d1 = -fy*y*zi*zi;
        // A = J_px_p @ [I3 | -skew(p3d)]   (2 x 6)
        const float A0[6] = {a0, 0.f, b0, b0*y, a0*z - b0*x, -a0*y};
        const float A1[6] = {0.f, c1, d1, -c1*z + d1*y, -d1*x, c1*x};
        #pragma unroll
        for (int i=0;i<6;i++) v[i] = A0[i]*sx + A1[i]*sy;
        int idx=6;
        #pragma unroll
        for (int i=0;i<6;i++){
            #pragma unroll
            for (int j=i;j<6;j++){
                v[idx] = gxx*A0[i]*A0[j]
                       + gxy*(A0[i]*A1[j]+A1[i]*A0[j])
                       + gyy*A1[i]*A1[j];
                idx++;
            }
        }
    }

    // wave reduce (8 points/wave) then block reduce (4 waves)
    __shared__ float wpart[4][NPART];
    const int wid  = tid >> 6;
    const int lane = tid & 63;
    #pragma unroll
    for (int i=0;i<NPART;i++){
        float vv = v[i];
        vv += __shfl_xor(vv, 8);
        vv += __shfl_xor(vv, 16);
        vv += __shfl_xor(vv, 32);
        if (lane==0) wpart[wid][i]=vv;
    }
    __syncthreads();
    if (tid < NPART){
        partials[blockIdx.x*NPART + tid] =
            wpart[0][tid]+wpart[1][tid]+wpart[2][tid]+wpart[3][tid];
    }
}

// Reduce partials, damp, solve 6x6, so3exp, update R,t. Single tiny block.
__global__ void pnp_solve(const float* __restrict__ partials,
                          const float* __restrict__ Rsrc,
                          const float* __restrict__ tsrc,
                          float* __restrict__ RtWs,
                          float* __restrict__ outp)
{
    __shared__ double red[NPART];
    const int t = threadIdx.x;
    if (t < NPART){
        double s = 0.0;
        for (int p=0;p<NBLK;p++) s += (double)partials[p*NPART + t];
        red[t] = s;
    }
    __syncthreads();
    if (t==0){
        double gv[6]; double H[6][6];
        for (int i=0;i<6;i++) gv[i]=red[i];
        int idx=6;
        for (int i=0;i<6;i++)
            for (int j=i;j<6;j++){
                H[i][j]=red[idx]; H[j][i]=red[idx]; idx++;
            }
        // H += LAMBDA * diag(diag(H) + 1e-9)
        for (int i=0;i<6;i++) H[i][i] += 0.01*(H[i][i] + 1e-9);

        // Gaussian elimination with partial pivoting: H * xs = gv
        double M[6][6], b[6];
        for (int i=0;i<6;i++){ b[i]=gv[i]; for (int j=0;j<6;j++) M[i][j]=H[i][j]; }
        for (int c=0;c<6;c++){
            int piv=c; double mx=fabs(M[c][c]);
            for (int r=c+1;r<6;r++){ double av=fabs(M[r][c]); if (av>mx){mx=av;piv=r;} }
            if (piv!=c){
                for (int j=c;j<6;j++){ double tmp=M[c][j]; M[c][j]=M[piv][j]; M[piv][j]=tmp; }
                double tb=b[c]; b[c]=b[piv]; b[piv]=tb;
            }
            const double inv = 1.0/M[c][c];
            for (int r=c+1;r<6;r++){
                const double f = M[r][c]*inv;
                for (int j=c;j<6;j++) M[r][j] -= f*M[c][j];
                b[r] -= f*b[c];
            }
        }
        double xs[6];
        for (int r=5;r>=0;r--){
            double s2=b[r];
            for (int j=r+1;j<6;j++) s2 -= M[r][j]*xs[j];
            xs[r]=s2/M[r][r];
        }
        double delta[6];
        for (int i=0;i<6;i++) delta[i] = -xs[i];

        // dR = so3exp(delta[3:])
        const double wx=delta[3], wy=delta[4], wz=delta[5];
        const double th = sqrt(wx*wx+wy*wy+wz*wz + 1e-24);
        const double Ath = sin(th)/th;
        const double Bth = (1.0-cos(th))/(th*th);
        const double W[3][3] = {{0.0,-wz,wy},{wz,0.0,-wx},{-wy,wx,0.0}};
        double W2[3][3];
        for (int i=0;i<3;i++) for (int j=0;j<3;j++){
            double s2=0; for (int k2=0;k2<3;k2++) s2 += W[i][k2]*W[k2][j];
            W2[i][j]=s2;
        }
        double dR[3][3];
        for (int i=0;i<3;i++) for (int j=0;j<3;j++)
            dR[i][j] = (i==j?1.0:0.0) + Ath*W[i][j] + Bth*W2[i][j];

        double Ro[3][3];
        for (int i=0;i<3;i++) for (int j=0;j<3;j++) Ro[i][j]=(double)Rsrc[i*3+j];
        const double to0=(double)tsrc[0], to1=(double)tsrc[1], to2=(double)tsrc[2];

        double Rn[3][3], tn[3];
        for (int i=0;i<3;i++){
            for (int j=0;j<3;j++){
                double s2=0; for (int k2=0;k2<3;k2++) s2 += dR[i][k2]*Ro[k2][j];
                Rn[i][j]=s2;
            }
            tn[i] = dR[i][0]*to0 + dR[i][1]*to1 + dR[i][2]*to2 + delta[i];
        }
        for (int i=0;i<3;i++) for (int j=0;j<3;j++){
            RtWs[i*3+j] = (float)Rn[i][j];
            outp[i*3+j] = (float)Rn[i][j];
        }
        for (int i=0;i<3;i++){ RtWs[9+i]=(float)tn[i]; outp[9+i]=(float)tn[i]; }
    }
}

extern "C" void kernel_launch(void* const* d_in, const int* in_sizes, int n_in,
                              void* d_out, int out_size, void* d_ws, size_t ws_size,
                              hipStream_t stream)
{
    const float* pts   = (const float*)d_in[0];
    const float* fref  = (const float*)d_in[1];
    const float* fmap  = (const float*)d_in[2];
    const float* gxm   = (const float*)d_in[3];
    const float* gym   = (const float*)d_in[4];
    const float* Kmat  = (const float*)d_in[5];
    const float* Rin   = (const float*)d_in[6];
    const float* tin   = (const float*)d_in[7];
    float* outp = (float*)d_out;
    float* partials = (float*)d_ws;
    float* RtWs = partials + NBLK*NPART;   // 12 floats of R,t state

    const float* Rs = Rin;
    const float* ts = tin;
    for (int it=0; it<5; ++it){
        pnp_accum<<<NBLK, 256, 0, stream>>>(pts, fref, fmap, gxm, gym,
                                            Kmat, Rs, ts, partials);
        pnp_solve<<<1, 64, 0, stream>>>(partials, Rs, ts, RtWs, outp);
        Rs = RtWs; ts = RtWs + 9;
    }
}

// Round 2
// 399.347 us; speedup vs baseline: 3.0828x; 3.0828x over previous
//
#include <hip/hip_runtime.h>
#include <math.h>

#define NPTS   32768
#define CCH    128
#define FMH    480
#define FMW    640
#define PLANE  (FMH*FMW)
#define IMW    640
#define IMH    480
#define TPP    8           // threads per point
#define PPB    32          // points per block
#define NBLK   (NPTS/PPB)  // 1024
#define NPART  27          // 6 (g) + 21 (H upper triangle)
#define LPAD   65          // LDS transpose pad (128 x 65 floats)

// ---------------------------------------------------------------------------
// One-time prep: per-pixel maps + (H*W, C) transposes of gx, gy.
// Block = 256 threads handles a 64-pixel tile across all 128 channels.
// Reads fmap/gx/gy fully coalesced; writes transposed rows coalesced.
// ---------------------------------------------------------------------------
__global__ __launch_bounds__(256)
void pnp_prep(const float* __restrict__ fmap,
              const float* __restrict__ gxm,
              const float* __restrict__ gym,
              float* __restrict__ gxT,
              float* __restrict__ gyT,
              float* __restrict__ maps)
{
    __shared__ float tgx[128*LPAD];
    __shared__ float tgy[128*LPAD];
    __shared__ float spart[4][5][64];
    const int tid = threadIdx.x;
    const int p   = tid & 63;           // pixel slot in tile (fixed per thread)
    const int cw  = tid >> 6;           // channel phase 0..3
    const size_t p0 = (size_t)blockIdx.x * 64;

    float sgxf=0.f, sgyf=0.f, sxx=0.f, sxy=0.f, syy=0.f;
    #pragma unroll 4
    for (int rep=0; rep<32; ++rep){
        const int c = rep*4 + cw;
        const size_t off = (size_t)c*PLANE + p0 + p;
        const float fv = fmap[off];
        const float a  = gxm[off];
        const float b  = gym[off];
        tgx[c*LPAD + p] = a;
        tgy[c*LPAD + p] = b;
        sgxf = fmaf(a, fv, sgxf);
        sgyf = fmaf(b, fv, sgyf);
        sxx  = fmaf(a, a, sxx);
        sxy  = fmaf(a, b, sxy);
        syy  = fmaf(b, b, syy);
    }
    spart[cw][0][p]=sgxf; spart[cw][1][p]=sgyf; spart[cw][2][p]=sxx;
    spart[cw][3][p]=sxy;  spart[cw][4][p]=syy;
    __syncthreads();

    if (tid < 64){
        #pragma unroll
        for (int m=0;m<5;m++){
            maps[(size_t)m*PLANE + p0 + tid] =
                spart[0][m][tid]+spart[1][m][tid]+spart[2][m][tid]+spart[3][m][tid];
        }
    }
    // transposed writes: wave writes 64 consecutive channels of one pixel row
    #pragma unroll 4
    for (int rep=0; rep<32; ++rep){
        const int idx = rep*256 + tid;
        const int pp  = idx >> 7;       // 0..63
        const int c   = idx & 127;
        gxT[(p0+pp)*CCH + c] = tgx[c*LPAD + pp];
        gyT[(p0+pp)*CCH + c] = tgy[c*LPAD + pp];
    }
}

// ---------------------------------------------------------------------------
// Per-iteration accumulate using transposed grads + pixel maps.
// ---------------------------------------------------------------------------
__global__ __launch_bounds__(256)
void pnp_accum2(const float* __restrict__ pts3D,
                const float* __restrict__ fref,
                const float* __restrict__ gxT,
                const float* __restrict__ gyT,
                const float* __restrict__ maps,
                const float* __restrict__ Kmat,
                const float* __restrict__ Rsrc,
                const float* __restrict__ tsrc,
                float* __restrict__ partials)
{
    const int tid = threadIdx.x;
    const int g   = tid & (TPP-1);
    const int pl  = tid >> 3;
    const int n   = blockIdx.x * PPB + pl;

    const float R00=Rsrc[0],R01=Rsrc[1],R02=Rsrc[2];
    const float R10=Rsrc[3],R11=Rsrc[4],R12=Rsrc[5];
    const float R20=Rsrc[6],R21=Rsrc[7],R22=Rsrc[8];
    const float t0=tsrc[0],t1=tsrc[1],t2=tsrc[2];
    const float K00=Kmat[0],K01=Kmat[1],K02=Kmat[2];
    const float K10=Kmat[3],K11=Kmat[4],K12=Kmat[5];
    const float K20=Kmat[6],K21=Kmat[7],K22=Kmat[8];
    const float fx=K00, fy=K11;

    const float px=pts3D[n*3+0], py=pts3D[n*3+1], pz=pts3D[n*3+2];
    const float x = R00*px + R01*py + R02*pz + t0;
    const float y = R10*px + R11*py + R12*pz + t1;
    const float z = R20*px + R21*py + R22*pz + t2;
    const float phx = K00*x + K01*y + K02*z;
    const float phy = K10*x + K11*y + K12*z;
    const float phz = K20*x + K21*y + K22*z;
    const int p2x = (int)rintf(phx/phz) - 1;
    const int p2y = (int)rintf(phy/phz) - 1;
    const bool inb = (p2x>=0) && (p2y>=0) && (p2x<IMW) && (p2y<IMH);

    float dx=0.f, dy=0.f;
    if (inb) {
        const size_t base = (size_t)(p2y*FMW + p2x) * CCH;
        const float4* gxp = reinterpret_cast<const float4*>(gxT + base) + g*4;
        const float4* gyp = reinterpret_cast<const float4*>(gyT + base) + g*4;
        const float4* rfp = reinterpret_cast<const float4*>(fref + (size_t)n*CCH) + g*4;
        #pragma unroll
        for (int j=0;j<4;j++){
            const float4 a = gxp[j];
            const float4 b = gyp[j];
            const float4 r = rfp[j];
            dx = fmaf(a.x,r.x,dx); dx = fmaf(a.y,r.y,dx);
            dx = fmaf(a.z,r.z,dx); dx = fmaf(a.w,r.w,dx);
            dy = fmaf(b.x,r.x,dy); dy = fmaf(b.y,r.y,dy);
            dy = fmaf(b.z,r.z,dy); dy = fmaf(b.w,r.w,dy);
        }
    }
    // reduce dot products across the point's 8 lanes
    #pragma unroll
    for (int d=1; d<TPP; d<<=1){
        dx += __shfl_xor(dx, d);
        dy += __shfl_xor(dy, d);
    }

    float v[NPART];
    #pragma unroll
    for (int i=0;i<NPART;i++) v[i]=0.f;
    if (inb) {
        const int pix = p2y*FMW + p2x;
        const float sx  = maps[0*PLANE+pix] - dx;
        const float sy  = maps[1*PLANE+pix] - dy;
        const float gxx = maps[2*PLANE+pix];
        const float gxy = maps[3*PLANE+pix];
        const float gyy = maps[4*PLANE+pix];

        const float zi = 1.f/z;
        const float a0 = fx*zi;
        const float b0 = -fx*x*zi*zi;
        const float c1 = fy*zi;
        const float d1 = -fy*y*zi*zi;
        const float A0[6] = {a0, 0.f, b0, b0*y, a0*z - b0*x, -a0*y};
        const float A1[6] = {0.f, c1, d1, -c1*z + d1*y, -d1*x, c1*x};
        #pragma unroll
        for (int i=0;i<6;i++) v[i] = A0[i]*sx + A1[i]*sy;
        int idx=6;
        #pragma unroll
        for (int i=0;i<6;i++){
            #pragma unroll
            for (int j=i;j<6;j++){
                v[idx] = gxx*A0[i]*A0[j]
                       + gxy*(A0[i]*A1[j]+A1[i]*A0[j])
                       + gyy*A1[i]*A1[j];
                idx++;
            }
        }
    }

    __shared__ float wpart[4][NPART];
    const int wid  = tid >> 6;
    const int lane = tid & 63;
    #pragma unroll
    for (int i=0;i<NPART;i++){
        float vv = v[i];
        vv += __shfl_xor(vv, 8);
        vv += __shfl_xor(vv, 16);
        vv += __shfl_xor(vv, 32);
        if (lane==0) wpart[wid][i]=vv;
    }
    __syncthreads();
    if (tid < NPART){
        partials[blockIdx.x*NPART + tid] =
            wpart[0][tid]+wpart[1][tid]+wpart[2][tid]+wpart[3][tid];
    }
}

// ---------------------------------------------------------------------------
// Fallback accum (round-1 path) if workspace is too small for transposes.
// ---------------------------------------------------------------------------
__global__ __launch_bounds__(256)
void pnp_accum(const float* __restrict__ pts3D,
               const float* __restrict__ fref,
               const float* __restrict__ fmap,
               const float* __restrict__ gxm,
               const float* __restrict__ gym,
               const float* __restrict__ Kmat,
               const float* __restrict__ Rsrc,
               const float* __restrict__ tsrc,
               float* __restrict__ partials)
{
    const int tid = threadIdx.x;
    const int g   = tid & (TPP-1);
    const int pl  = tid >> 3;
    const int n   = blockIdx.x * PPB + pl;

    const float R00=Rsrc[0],R01=Rsrc[1],R02=Rsrc[2];
    const float R10=Rsrc[3],R11=Rsrc[4],R12=Rsrc[5];
    const float R20=Rsrc[6],R21=Rsrc[7],R22=Rsrc[8];
    const float t0=tsrc[0],t1=tsrc[1],t2=tsrc[2];
    const float K00=Kmat[0],K01=Kmat[1],K02=Kmat[2];
    const float K10=Kmat[3],K11=Kmat[4],K12=Kmat[5];
    const float K20=Kmat[6],K21=Kmat[7],K22=Kmat[8];
    const float fx=K00, fy=K11;

    const float px=pts3D[n*3+0], py=pts3D[n*3+1], pz=pts3D[n*3+2];
    const float x = R00*px + R01*py + R02*pz + t0;
    const float y = R10*px + R11*py + R12*pz + t1;
    const float z = R20*px + R21*py + R22*pz + t2;
    const float phx = K00*x + K01*y + K02*z;
    const float phy = K10*x + K11*y + K12*z;
    const float phz = K20*x + K21*y + K22*z;
    const int p2x = (int)rintf(phx/phz) - 1;
    const int p2y = (int)rintf(phy/phz) - 1;
    const bool inb = (p2x>=0) && (p2y>=0) && (p2x<IMW) && (p2y<IMH);

    float sx=0.f, sy=0.f, gxx=0.f, gxy=0.f, gyy=0.f;
    if (inb) {
        const int pix = p2y*FMW + p2x;
        const float* fm = fmap + pix;
        const float* gx = gxm  + pix;
        const float* gy = gym  + pix;
        const float4* refp =
            reinterpret_cast<const float4*>(fref + (size_t)n*CCH + g*16);
        #pragma unroll
        for (int j=0;j<4;j++){
            const float4 rv = refp[j];
            const float rarr[4] = {rv.x, rv.y, rv.z, rv.w};
            const int c0 = g*16 + j*4;
            #pragma unroll
            for (int k=0;k<4;k++){
                const int off = (c0+k)*PLANE;
                const float f = fm[off];
                const float a = gx[off];
                const float b = gy[off];
                const float e = f - rarr[k];
                sx  = fmaf(a,e,sx);
                sy  = fmaf(b,e,sy);
                gxx = fmaf(a,a,gxx);
                gxy = fmaf(a,b,gxy);
                gyy = fmaf(b,b,gyy);
            }
        }
    }
    #pragma unroll
    for (int d=1; d<TPP; d<<=1){
        sx  += __shfl_xor(sx , d);
        sy  += __shfl_xor(sy , d);
        gxx += __shfl_xor(gxx, d);
        gxy += __shfl_xor(gxy, d);
        gyy += __shfl_xor(gyy, d);
    }

    float v[NPART];
    #pragma unroll
    for (int i=0;i<NPART;i++) v[i]=0.f;
    if (inb) {
        const float zi = 1.f/z;
        const float a0 = fx*zi;
        const float b0 = -fx*x*zi*zi;
        const float c1 = fy*zi;
        const float d1 = -fy*y*zi*zi;
        const float A0[6] = {a0, 0.f, b0, b0*y, a0*z - b0*x, -a0*y};
        const float A1[6] = {0.f, c1, d1, -c1*z + d1*y, -d1*x, c1*x};
        #pragma unroll
        for (int i=0;i<6;i++) v[i] = A0[i]*sx + A1[i]*sy;
        int idx=6;
        #pragma unroll
        for (int i=0;i<6;i++){
            #pragma unroll
            for (int j=i;j<6;j++){
                v[idx] = gxx*A0[i]*A0[j]
                       + gxy*(A0[i]*A1[j]+A1[i]*A0[j])
                       + gyy*A1[i]*A1[j];
                idx++;
            }
        }
    }

    __shared__ float wpart[4][NPART];
    const int wid  = tid >> 6;
    const int lane = tid & 63;
    #pragma unroll
    for (int i=0;i<NPART;i++){
        float vv = v[i];
        vv += __shfl_xor(vv, 8);
        vv += __shfl_xor(vv, 16);
        vv += __shfl_xor(vv, 32);
        if (lane==0) wpart[wid][i]=vv;
    }
    __syncthreads();
    if (tid < NPART){
        partials[blockIdx.x*NPART + tid] =
            wpart[0][tid]+wpart[1][tid]+wpart[2][tid]+wpart[3][tid];
    }
}

// ---------------------------------------------------------------------------
// Reduce partials, damp, solve 6x6, so3exp, update R,t. Single tiny block.
// ---------------------------------------------------------------------------
__global__ void pnp_solve(const float* __restrict__ partials,
                          const float* __restrict__ Rsrc,
                          const float* __restrict__ tsrc,
                          float* __restrict__ RtWs,
                          float* __restrict__ outp)
{
    __shared__ double red[NPART];
    const int t = threadIdx.x;
    if (t < NPART){
        double s = 0.0;
        for (int p=0;p<NBLK;p++) s += (double)partials[p*NPART + t];
        red[t] = s;
    }
    __syncthreads();
    if (t==0){
        double gv[6]; double H[6][6];
        for (int i=0;i<6;i++) gv[i]=red[i];
        int idx=6;
        for (int i=0;i<6;i++)
            for (int j=i;j<6;j++){
                H[i][j]=red[idx]; H[j][i]=red[idx]; idx++;
            }
        for (int i=0;i<6;i++) H[i][i] += 0.01*(H[i][i] + 1e-9);

        double M[6][6], b[6];
        for (int i=0;i<6;i++){ b[i]=gv[i]; for (int j=0;j<6;j++) M[i][j]=H[i][j]; }
        for (int c=0;c<6;c++){
            int piv=c; double mx=fabs(M[c][c]);
            for (int r=c+1;r<6;r++){ double av=fabs(M[r][c]); if (av>mx){mx=av;piv=r;} }
            if (piv!=c){
                for (int j=c;j<6;j++){ double tmp=M[c][j]; M[c][j]=M[piv][j]; M[piv][j]=tmp; }
                double tb=b[c]; b[c]=b[piv]; b[piv]=tb;
            }
            const double inv = 1.0/M[c][c];
            for (int r=c+1;r<6;r++){
                const double f = M[r][c]*inv;
                for (int j=c;j<6;j++) M[r][j] -= f*M[c][j];
                b[r] -= f*b[c];
            }
        }
        double xs[6];
        for (int r=5;r>=0;r--){
            double s2=b[r];
            for (int j=r+1;j<6;j++) s2 -= M[r][j]*xs[j];
            xs[r]=s2/M[r][r];
        }
        double delta[6];
        for (int i=0;i<6;i++) delta[i] = -xs[i];

        const double wx=delta[3], wy=delta[4], wz=delta[5];
        const double th = sqrt(wx*wx+wy*wy+wz*wz + 1e-24);
        const double Ath = sin(th)/th;
        const double Bth = (1.0-cos(th))/(th*th);
        const double W[3][3] = {{0.0,-wz,wy},{wz,0.0,-wx},{-wy,wx,0.0}};
        double W2[3][3];
        for (int i=0;i<3;i++) for (int j=0;j<3;j++){
            double s2=0; for (int k2=0;k2<3;k2++) s2 += W[i][k2]*W[k2][j];
            W2[i][j]=s2;
        }
        double dR[3][3];
        for (int i=0;i<3;i++) for (int j=0;j<3;j++)
            dR[i][j] = (i==j?1.0:0.0) + Ath*W[i][j] + Bth*W2[i][j];

        double Ro[3][3];
        for (int i=0;i<3;i++) for (int j=0;j<3;j++) Ro[i][j]=(double)Rsrc[i*3+j];
        const double to0=(double)tsrc[0], to1=(double)tsrc[1], to2=(double)tsrc[2];

        double Rn[3][3], tn[3];
        for (int i=0;i<3;i++){
            for (int j=0;j<3;j++){
                double s2=0; for (int k2=0;k2<3;k2++) s2 += dR[i][k2]*Ro[k2][j];
                Rn[i][j]=s2;
            }
            tn[i] = dR[i][0]*to0 + dR[i][1]*to1 + dR[i][2]*to2 + delta[i];
        }
        for (int i=0;i<3;i++) for (int j=0;j<3;j++){
            RtWs[i*3+j] = (float)Rn[i][j];
            outp[i*3+j] = (float)Rn[i][j];
        }
        for (int i=0;i<3;i++){ RtWs[9+i]=(float)tn[i]; outp[9+i]=(float)tn[i]; }
    }
}

extern "C" void kernel_launch(void* const* d_in, const int* in_sizes, int n_in,
                              void* d_out, int out_size, void* d_ws, size_t ws_size,
                              hipStream_t stream)
{
    const float* pts   = (const float*)d_in[0];
    const float* fref  = (const float*)d_in[1];
    const float* fmap  = (const float*)d_in[2];
    const float* gxm   = (const float*)d_in[3];
    const float* gym   = (const float*)d_in[4];
    const float* Kmat  = (const float*)d_in[5];
    const float* Rin   = (const float*)d_in[6];
    const float* tin   = (const float*)d_in[7];
    float* outp = (float*)d_out;

    // workspace layout: [partials][RtWs][maps(5*PLANE)][gxT][gyT]
    float* partials = (float*)d_ws;
    float* RtWs = partials + NBLK*NPART;
    float* maps = RtWs + 12;
    float* gxT  = maps + (size_t)5*PLANE;
    float* gyT  = gxT + (size_t)PLANE*CCH;
    const size_t needed = ((size_t)NBLK*NPART + 12 + (size_t)5*PLANE
                           + 2*(size_t)PLANE*CCH) * sizeof(float);

    const bool fast = (ws_size >= needed);
    if (fast){
        pnp_prep<<<PLANE/64, 256, 0, stream>>>(fmap, gxm, gym, gxT, gyT, maps);
    }

    const float* Rs = Rin;
    const float* ts = tin;
    for (int it=0; it<5; ++it){
        if (fast){
            pnp_accum2<<<NBLK, 256, 0, stream>>>(pts, fref, gxT, gyT, maps,
                                                 Kmat, Rs, ts, partials);
        } else {
            pnp_accum<<<NBLK, 256, 0, stream>>>(pts, fref, fmap, gxm, gym,
                                                Kmat, Rs, ts, partials);
        }
        pnp_solve<<<1, 64, 0, stream>>>(partials, Rs, ts, RtWs, outp);
        Rs = RtWs; ts = RtWs + 9;
    }
}

// Round 3
// 300.613 us; speedup vs baseline: 4.0953x; 1.3284x over previous
//
#include <hip/hip_runtime.h>
#include <hip/hip_fp16.h>
#include <math.h>

#define NPTS   32768
#define CCH    128
#define FMH    480
#define FMW    640
#define PLANE  (FMH*FMW)
#define IMW    640
#define IMH    480
#define TPP    8           // threads per point
#define PPB    32          // points per block
#define NBLK   (NPTS/PPB)  // 1024
#define NPART  27          // 6 (g) + 21 (H upper triangle)
#define TPAD   130         // LDS pad for 64x128 half2 tile ([pix][ch])
#define MSTR   8           // per-pixel map stride (floats)

// ---------------------------------------------------------------------------
// One-time prep: per-pixel maps + (H*W, C) fp16-interleaved transpose of gx,gy.
// Block = 256 threads handles a 64-pixel tile across all 128 channels.
// ---------------------------------------------------------------------------
__global__ __launch_bounds__(256)
void pnp_prep(const float* __restrict__ fmap,
              const float* __restrict__ gxm,
              const float* __restrict__ gym,
              __half2* __restrict__ gT,
              float* __restrict__ maps8)
{
    __shared__ __half2 tg[64*TPAD];        // 33,280 B
    __shared__ float spart[4][5][64];      //  5,120 B
    const int tid = threadIdx.x;
    const int p   = tid & 63;           // pixel slot in tile
    const int cw  = tid >> 6;           // channel phase 0..3
    const size_t p0 = (size_t)blockIdx.x * 64;

    float sgxf=0.f, sgyf=0.f, sxx=0.f, sxy=0.f, syy=0.f;
    #pragma unroll 4
    for (int rep=0; rep<32; ++rep){
        const int c = rep*4 + cw;
        const size_t off = (size_t)c*PLANE + p0 + p;
        const float fv = fmap[off];
        const float a  = gxm[off];
        const float b  = gym[off];
        tg[p*TPAD + c] = __floats2half2_rn(a, b);
        sgxf = fmaf(a, fv, sgxf);
        sgyf = fmaf(b, fv, sgyf);
        sxx  = fmaf(a, a, sxx);
        sxy  = fmaf(a, b, sxy);
        syy  = fmaf(b, b, syy);
    }
    spart[cw][0][p]=sgxf; spart[cw][1][p]=sgyf; spart[cw][2][p]=sxx;
    spart[cw][3][p]=sxy;  spart[cw][4][p]=syy;
    __syncthreads();

    if (tid < 64){
        const size_t pix = p0 + tid;
        const float m0 = spart[0][0][tid]+spart[1][0][tid]+spart[2][0][tid]+spart[3][0][tid];
        const float m1 = spart[0][1][tid]+spart[1][1][tid]+spart[2][1][tid]+spart[3][1][tid];
        const float m2 = spart[0][2][tid]+spart[1][2][tid]+spart[2][2][tid]+spart[3][2][tid];
        const float m3 = spart[0][3][tid]+spart[1][3][tid]+spart[2][3][tid]+spart[3][3][tid];
        const float m4 = spart[0][4][tid]+spart[1][4][tid]+spart[2][4][tid]+spart[3][4][tid];
        float4 v4; v4.x=m0; v4.y=m1; v4.z=m2; v4.w=m3;
        *reinterpret_cast<float4*>(&maps8[pix*MSTR]) = v4;
        maps8[pix*MSTR + 4] = m4;
    }

    // transposed writes: 16 reps, 4 pixels/rep, 64 threads per pixel row,
    // each thread moves 2 half2 (8 B) -> wave writes 512 B contiguous.
    #pragma unroll 4
    for (int rep=0; rep<16; ++rep){
        const int idx = rep*256 + tid;
        const int pp  = idx >> 6;          // 0..63
        const int c0  = (idx & 63) * 2;    // channel pair base
        const uint2 w = *reinterpret_cast<const uint2*>(&tg[pp*TPAD + c0]);
        *reinterpret_cast<uint2*>(&gT[(p0+pp)*CCH + c0]) = w;
    }
}

// ---------------------------------------------------------------------------
// Per-iteration accumulate using fp16 transposed grads + packed pixel maps.
// ---------------------------------------------------------------------------
__global__ __launch_bounds__(256)
void pnp_accum2(const float* __restrict__ pts3D,
                const float* __restrict__ fref,
                const __half2* __restrict__ gT,
                const float* __restrict__ maps8,
                const float* __restrict__ Kmat,
                const float* __restrict__ Rsrc,
                const float* __restrict__ tsrc,
                float* __restrict__ partials)
{
    const int tid = threadIdx.x;
    const int g   = tid & (TPP-1);
    const int pl  = tid >> 3;
    const int n   = blockIdx.x * PPB + pl;

    const float R00=Rsrc[0],R01=Rsrc[1],R02=Rsrc[2];
    const float R10=Rsrc[3],R11=Rsrc[4],R12=Rsrc[5];
    const float R20=Rsrc[6],R21=Rsrc[7],R22=Rsrc[8];
    const float t0=tsrc[0],t1=tsrc[1],t2=tsrc[2];
    const float K00=Kmat[0],K01=Kmat[1],K02=Kmat[2];
    const float K10=Kmat[3],K11=Kmat[4],K12=Kmat[5];
    const float K20=Kmat[6],K21=Kmat[7],K22=Kmat[8];
    const float fx=K00, fy=K11;

    const float px=pts3D[n*3+0], py=pts3D[n*3+1], pz=pts3D[n*3+2];
    const float x = R00*px + R01*py + R02*pz + t0;
    const float y = R10*px + R11*py + R12*pz + t1;
    const float z = R20*px + R21*py + R22*pz + t2;
    const float phx = K00*x + K01*y + K02*z;
    const float phy = K10*x + K11*y + K12*z;
    const float phz = K20*x + K21*y + K22*z;
    const int p2x = (int)rintf(phx/phz) - 1;
    const int p2y = (int)rintf(phy/phz) - 1;
    const bool inb = (p2x>=0) && (p2y>=0) && (p2x<IMW) && (p2y<IMH);
    const int pix = inb ? (p2y*FMW + p2x) : 0;

    float dx=0.f, dy=0.f;
    if (inb) {
        const uint4*  gp = reinterpret_cast<const uint4*>(gT + (size_t)pix*CCH + g*16);
        const float4* rp = reinterpret_cast<const float4*>(fref + (size_t)n*CCH + g*16);
        #pragma unroll
        for (int j=0;j<4;j++){
            const uint4  w = gp[j];
            const float4 r = rp[j];
            const float2 f0 = __half22float2(*reinterpret_cast<const __half2*>(&w.x));
            const float2 f1 = __half22float2(*reinterpret_cast<const __half2*>(&w.y));
            const float2 f2 = __half22float2(*reinterpret_cast<const __half2*>(&w.z));
            const float2 f3 = __half22float2(*reinterpret_cast<const __half2*>(&w.w));
            dx = fmaf(f0.x,r.x,dx); dy = fmaf(f0.y,r.x,dy);
            dx = fmaf(f1.x,r.y,dx); dy = fmaf(f1.y,r.y,dy);
            dx = fmaf(f2.x,r.z,dx); dy = fmaf(f2.y,r.z,dy);
            dx = fmaf(f3.x,r.w,dx); dy = fmaf(f3.y,r.w,dy);
        }
    }
    #pragma unroll
    for (int d=1; d<TPP; d<<=1){
        dx += __shfl_xor(dx, d);
        dy += __shfl_xor(dy, d);
    }

    float v[NPART];
    #pragma unroll
    for (int i=0;i<NPART;i++) v[i]=0.f;
    if (inb) {
        const float4 m03 = *reinterpret_cast<const float4*>(&maps8[(size_t)pix*MSTR]);
        const float  m4  = maps8[(size_t)pix*MSTR + 4];
        const float sx  = m03.x - dx;
        const float sy  = m03.y - dy;
        const float gxx = m03.z;
        const float gxy = m03.w;
        const float gyy = m4;

        const float zi = 1.f/z;
        const float a0 = fx*zi;
        const float b0 = -fx*x*zi*zi;
        const float c1 = fy*zi;
        const float d1 = -fy*y*zi*zi;
        const float A0[6] = {a0, 0.f, b0, b0*y, a0*z - b0*x, -a0*y};
        const float A1[6] = {0.f, c1, d1, -c1*z + d1*y, -d1*x, c1*x};
        #pragma unroll
        for (int i=0;i<6;i++) v[i] = A0[i]*sx + A1[i]*sy;
        int idx=6;
        #pragma unroll
        for (int i=0;i<6;i++){
            #pragma unroll
            for (int j=i;j<6;j++){
                v[idx] = gxx*A0[i]*A0[j]
                       + gxy*(A0[i]*A1[j]+A1[i]*A0[j])
                       + gyy*A1[i]*A1[j];
                idx++;
            }
        }
    }

    __shared__ float wpart[4][NPART];
    const int wid  = tid >> 6;
    const int lane = tid & 63;
    #pragma unroll
    for (int i=0;i<NPART;i++){
        float vv = v[i];
        vv += __shfl_xor(vv, 8);
        vv += __shfl_xor(vv, 16);
        vv += __shfl_xor(vv, 32);
        if (lane==0) wpart[wid][i]=vv;
    }
    __syncthreads();
    if (tid < NPART){
        partials[blockIdx.x*NPART + tid] =
            wpart[0][tid]+wpart[1][tid]+wpart[2][tid]+wpart[3][tid];
    }
}

// ---------------------------------------------------------------------------
// Fallback accum (round-1 path) if workspace is too small for transposes.
// ---------------------------------------------------------------------------
__global__ __launch_bounds__(256)
void pnp_accum(const float* __restrict__ pts3D,
               const float* __restrict__ fref,
               const float* __restrict__ fmap,
               const float* __restrict__ gxm,
               const float* __restrict__ gym,
               const float* __restrict__ Kmat,
               const float* __restrict__ Rsrc,
               const float* __restrict__ tsrc,
               float* __restrict__ partials)
{
    const int tid = threadIdx.x;
    const int g   = tid & (TPP-1);
    const int pl  = tid >> 3;
    const int n   = blockIdx.x * PPB + pl;

    const float R00=Rsrc[0],R01=Rsrc[1],R02=Rsrc[2];
    const float R10=Rsrc[3],R11=Rsrc[4],R12=Rsrc[5];
    const float R20=Rsrc[6],R21=Rsrc[7],R22=Rsrc[8];
    const float t0=tsrc[0],t1=tsrc[1],t2=tsrc[2];
    const float K00=Kmat[0],K01=Kmat[1],K02=Kmat[2];
    const float K10=Kmat[3],K11=Kmat[4],K12=Kmat[5];
    const float K20=Kmat[6],K21=Kmat[7],K22=Kmat[8];
    const float fx=K00, fy=K11;

    const float px=pts3D[n*3+0], py=pts3D[n*3+1], pz=pts3D[n*3+2];
    const float x = R00*px + R01*py + R02*pz + t0;
    const float y = R10*px + R11*py + R12*pz + t1;
    const float z = R20*px + R21*py + R22*pz + t2;
    const float phx = K00*x + K01*y + K02*z;
    const float phy = K10*x + K11*y + K12*z;
    const float phz = K20*x + K21*y + K22*z;
    const int p2x = (int)rintf(phx/phz) - 1;
    const int p2y = (int)rintf(phy/phz) - 1;
    const bool inb = (p2x>=0) && (p2y>=0) && (p2x<IMW) && (p2y<IMH);

    float sx=0.f, sy=0.f, gxx=0.f, gxy=0.f, gyy=0.f;
    if (inb) {
        const int pix = p2y*FMW + p2x;
        const float* fm = fmap + pix;
        const float* gx = gxm  + pix;
        const float* gy = gym  + pix;
        const float4* refp =
            reinterpret_cast<const float4*>(fref + (size_t)n*CCH + g*16);
        #pragma unroll
        for (int j=0;j<4;j++){
            const float4 rv = refp[j];
            const float rarr[4] = {rv.x, rv.y, rv.z, rv.w};
            const int c0 = g*16 + j*4;
            #pragma unroll
            for (int k=0;k<4;k++){
                const int off = (c0+k)*PLANE;
                const float f = fm[off];
                const float a = gx[off];
                const float b = gy[off];
                const float e = f - rarr[k];
                sx  = fmaf(a,e,sx);
                sy  = fmaf(b,e,sy);
                gxx = fmaf(a,a,gxx);
                gxy = fmaf(a,b,gxy);
                gyy = fmaf(b,b,gyy);
            }
        }
    }
    #pragma unroll
    for (int d=1; d<TPP; d<<=1){
        sx  += __shfl_xor(sx , d);
        sy  += __shfl_xor(sy , d);
        gxx += __shfl_xor(gxx, d);
        gxy += __shfl_xor(gxy, d);
        gyy += __shfl_xor(gyy, d);
    }

    float v[NPART];
    #pragma unroll
    for (int i=0;i<NPART;i++) v[i]=0.f;
    if (inb) {
        const float zi = 1.f/z;
        const float a0 = fx*zi;
        const float b0 = -fx*x*zi*zi;
        const float c1 = fy*zi;
        const float d1 = -fy*y*zi*zi;
        const float A0[6] = {a0, 0.f, b0, b0*y, a0*z - b0*x, -a0*y};
        const float A1[6] = {0.f, c1, d1, -c1*z + d1*y, -d1*x, c1*x};
        #pragma unroll
        for (int i=0;i<6;i++) v[i] = A0[i]*sx + A1[i]*sy;
        int idx=6;
        #pragma unroll
        for (int i=0;i<6;i++){
            #pragma unroll
            for (int j=i;j<6;j++){
                v[idx] = gxx*A0[i]*A0[j]
                       + gxy*(A0[i]*A1[j]+A1[i]*A0[j])
                       + gyy*A1[i]*A1[j];
                idx++;
            }
        }
    }

    __shared__ float wpart[4][NPART];
    const int wid  = tid >> 6;
    const int lane = tid & 63;
    #pragma unroll
    for (int i=0;i<NPART;i++){
        float vv = v[i];
        vv += __shfl_xor(vv, 8);
        vv += __shfl_xor(vv, 16);
        vv += __shfl_xor(vv, 32);
        if (lane==0) wpart[wid][i]=vv;
    }
    __syncthreads();
    if (tid < NPART){
        partials[blockIdx.x*NPART + tid] =
            wpart[0][tid]+wpart[1][tid]+wpart[2][tid]+wpart[3][tid];
    }
}

// ---------------------------------------------------------------------------
// Parallel-reduce partials, damp, solve 6x6, so3exp, update R,t.
// ---------------------------------------------------------------------------
__global__ void pnp_solve(const float* __restrict__ partials,
                          const float* __restrict__ Rsrc,
                          const float* __restrict__ tsrc,
                          float* __restrict__ RtWs,
                          float* __restrict__ outp)
{
    __shared__ double red[NPART*8];
    const int t = threadIdx.x;
    if (t < NPART*8){
        const int col = t % NPART;
        const int grp = t / NPART;
        double s0 = 0.0, s1 = 0.0;
        for (int p = grp; p < NBLK; p += 16){
            s0 += (double)partials[p*NPART + col];
            s1 += (double)partials[(p+8)*NPART + col];
        }
        red[col*8 + grp] = s0 + s1;
    }
    __syncthreads();
    if (t < NPART){
        double s = 0.0;
        #pragma unroll
        for (int k=0;k<8;k++) s += red[t*8 + k];
        red[t*8] = s;
    }
    __syncthreads();
    if (t==0){
        double gv[6]; double H[6][6];
        for (int i=0;i<6;i++) gv[i]=red[i*8];
        int idx=6;
        for (int i=0;i<6;i++)
            for (int j=i;j<6;j++){
                H[i][j]=red[idx*8]; H[j][i]=red[idx*8]; idx++;
            }
        for (int i=0;i<6;i++) H[i][i] += 0.01*(H[i][i] + 1e-9);

        double M[6][6], b[6];
        for (int i=0;i<6;i++){ b[i]=gv[i]; for (int j=0;j<6;j++) M[i][j]=H[i][j]; }
        for (int c=0;c<6;c++){
            int piv=c; double mx=fabs(M[c][c]);
            for (int r=c+1;r<6;r++){ double av=fabs(M[r][c]); if (av>mx){mx=av;piv=r;} }
            if (piv!=c){
                for (int j=c;j<6;j++){ double tmp=M[c][j]; M[c][j]=M[piv][j]; M[piv][j]=tmp; }
                double tb=b[c]; b[c]=b[piv]; b[piv]=tb;
            }
            const double inv = 1.0/M[c][c];
            for (int r=c+1;r<6;r++){
                const double f = M[r][c]*inv;
                for (int j=c;j<6;j++) M[r][j] -= f*M[c][j];
                b[r] -= f*b[c];
            }
        }
        double xs[6];
        for (int r=5;r>=0;r--){
            double s2=b[r];
            for (int j=r+1;j<6;j++) s2 -= M[r][j]*xs[j];
            xs[r]=s2/M[r][r];
        }
        double delta[6];
        for (int i=0;i<6;i++) delta[i] = -xs[i];

        const double wx=delta[3], wy=delta[4], wz=delta[5];
        const double th = sqrt(wx*wx+wy*wy+wz*wz + 1e-24);
        const double Ath = sin(th)/th;
        const double Bth = (1.0-cos(th))/(th*th);
        const double W[3][3] = {{0.0,-wz,wy},{wz,0.0,-wx},{-wy,wx,0.0}};
        double W2[3][3];
        for (int i=0;i<3;i++) for (int j=0;j<3;j++){
            double s2=0; for (int k2=0;k2<3;k2++) s2 += W[i][k2]*W[k2][j];
            W2[i][j]=s2;
        }
        double dR[3][3];
        for (int i=0;i<3;i++) for (int j=0;j<3;j++)
            dR[i][j] = (i==j?1.0:0.0) + Ath*W[i][j] + Bth*W2[i][j];

        double Ro[3][3];
        for (int i=0;i<3;i++) for (int j=0;j<3;j++) Ro[i][j]=(double)Rsrc[i*3+j];
        const double to0=(double)tsrc[0], to1=(double)tsrc[1], to2=(double)tsrc[2];

        double Rn[3][3], tn[3];
        for (int i=0;i<3;i++){
            for (int j=0;j<3;j++){
                double s2=0; for (int k2=0;k2<3;k2++) s2 += dR[i][k2]*Ro[k2][j];
                Rn[i][j]=s2;
            }
            tn[i] = dR[i][0]*to0 + dR[i][1]*to1 + dR[i][2]*to2 + delta[i];
        }
        for (int i=0;i<3;i++) for (int j=0;j<3;j++){
            RtWs[i*3+j] = (float)Rn[i][j];
            outp[i*3+j] = (float)Rn[i][j];
        }
        for (int i=0;i<3;i++){ RtWs[9+i]=(float)tn[i]; outp[9+i]=(float)tn[i]; }
    }
}

extern "C" void kernel_launch(void* const* d_in, const int* in_sizes, int n_in,
                              void* d_out, int out_size, void* d_ws, size_t ws_size,
                              hipStream_t stream)
{
    const float* pts   = (const float*)d_in[0];
    const float* fref  = (const float*)d_in[1];
    const float* fmap  = (const float*)d_in[2];
    const float* gxm   = (const float*)d_in[3];
    const float* gym   = (const float*)d_in[4];
    const float* Kmat  = (const float*)d_in[5];
    const float* Rin   = (const float*)d_in[6];
    const float* tin   = (const float*)d_in[7];
    float* outp = (float*)d_out;

    // workspace layout: [partials][RtWs][maps8(8*PLANE f32)][gT(PLANE*128 half2)]
    float* partials = (float*)d_ws;
    float* RtWs  = partials + NBLK*NPART;
    float* maps8 = RtWs + 12;
    __half2* gT  = reinterpret_cast<__half2*>(maps8 + (size_t)MSTR*PLANE);
    const size_t needed = ((size_t)NBLK*NPART + 12 + (size_t)MSTR*PLANE
                           + (size_t)PLANE*CCH) * sizeof(float) / 1
                           - (size_t)PLANE*CCH*0; // floats; gT is 4B/elem too
    const size_t needed_bytes = ((size_t)NBLK*NPART + 12 + (size_t)MSTR*PLANE) * 4
                                + (size_t)PLANE*CCH * sizeof(__half2);

    const bool fast = (ws_size >= needed_bytes);
    (void)needed;
    if (fast){
        pnp_prep<<<PLANE/64, 256, 0, stream>>>(fmap, gxm, gym, gT, maps8);
    }

    const float* Rs = Rin;
    const float* ts = tin;
    for (int it=0; it<5; ++it){
        if (fast){
            pnp_accum2<<<NBLK, 256, 0, stream>>>(pts, fref, gT, maps8,
                                                 Kmat, Rs, ts, partials);
        } else {
            pnp_accum<<<NBLK, 256, 0, stream>>>(pts, fref, fmap, gxm, gym,
                                                Kmat, Rs, ts, partials);
        }
        pnp_solve<<<1, 256, 0, stream>>>(partials, Rs, ts, RtWs, outp);
        Rs = RtWs; ts = RtWs + 9;
    }
}

// Round 4
// 297.431 us; speedup vs baseline: 4.1391x; 1.0107x over previous
//
#include <hip/hip_runtime.h>
#include <hip/hip_fp16.h>
#include <math.h>

#define NPTS   32768
#define CCH    128
#define FMH    480
#define FMW    640
#define PLANE  (FMH*FMW)
#define IMW    640
#define IMH    480
#define TPP    8           // threads per point
#define PPB    32          // points per block
#define NBLK   (NPTS/PPB)  // 1024
#define NPART  27          // 6 (g) + 21 (H upper triangle)
#define TPAD   130         // LDS pad for 64x128 half2 tile ([pix][ch])
#define MSTR   8           // per-pixel map stride (floats)

// ---------------------------------------------------------------------------
// One-time prep: per-pixel maps + (H*W, C) fp16-interleaved transpose of gx,gy.
// Block = 256 threads handles a 64-pixel tile across all 128 channels.
// Thread layout: pgrp = tid&15 (pixel quad), cph = tid>>4 (channel phase).
// All global reads are float4 (16 B/lane) for memory-level parallelism.
// ---------------------------------------------------------------------------
__global__ __launch_bounds__(256)
void pnp_prep(const float* __restrict__ fmap,
              const float* __restrict__ gxm,
              const float* __restrict__ gym,
              __half2* __restrict__ gT,
              float* __restrict__ maps8)
{
    __shared__ __half2 tg[64*TPAD];        // 33,280 B
    __shared__ float spart[4][5][64];      //  5,120 B
    const int tid  = threadIdx.x;
    const int pgrp = tid & 15;             // pixel quad 0..15
    const int cph  = tid >> 4;             // channel phase 0..15
    const int w    = tid >> 6;             // wave 0..3
    const int pq   = pgrp * 4;             // local pixel base 0..60
    const size_t p0 = (size_t)blockIdx.x * 64;

    float acc[5][4];
    #pragma unroll
    for (int m=0;m<5;m++)
        #pragma unroll
        for (int i=0;i<4;i++) acc[m][i]=0.f;

    #pragma unroll
    for (int rep=0; rep<8; ++rep){
        const int c = rep*16 + cph;
        const size_t off = (size_t)c*PLANE + p0 + pq;
        const float4 fv = *reinterpret_cast<const float4*>(fmap + off);
        const float4 av = *reinterpret_cast<const float4*>(gxm + off);
        const float4 bv = *reinterpret_cast<const float4*>(gym + off);
        const float fa[4]={fv.x,fv.y,fv.z,fv.w};
        const float xa[4]={av.x,av.y,av.z,av.w};
        const float ya[4]={bv.x,bv.y,bv.z,bv.w};
        #pragma unroll
        for (int i=0;i<4;i++){
            acc[0][i] = fmaf(xa[i], fa[i], acc[0][i]);
            acc[1][i] = fmaf(ya[i], fa[i], acc[1][i]);
            acc[2][i] = fmaf(xa[i], xa[i], acc[2][i]);
            acc[3][i] = fmaf(xa[i], ya[i], acc[3][i]);
            acc[4][i] = fmaf(ya[i], ya[i], acc[4][i]);
            tg[(pq+i)*TPAD + c] = __floats2half2_rn(xa[i], ya[i]);
        }
    }

    // reduce across the 16 channel phases: xor16/xor32 folds the 4 phases in
    // this wave (lane = (cph&3)*16 + pgrp), then LDS across the 4 waves.
    const bool lo16 = ((tid >> 4) & 3) == 0;
    #pragma unroll
    for (int m=0;m<5;m++){
        #pragma unroll
        for (int i=0;i<4;i++){
            float v = acc[m][i];
            v += __shfl_xor(v, 16);
            v += __shfl_xor(v, 32);
            if (lo16) spart[w][m][pq+i] = v;
        }
    }
    __syncthreads();

    if (tid < 64){
        const size_t pix = p0 + tid;
        const float m0 = spart[0][0][tid]+spart[1][0][tid]+spart[2][0][tid]+spart[3][0][tid];
        const float m1 = spart[0][1][tid]+spart[1][1][tid]+spart[2][1][tid]+spart[3][1][tid];
        const float m2 = spart[0][2][tid]+spart[1][2][tid]+spart[2][2][tid]+spart[3][2][tid];
        const float m3 = spart[0][3][tid]+spart[1][3][tid]+spart[2][3][tid]+spart[3][3][tid];
        const float m4 = spart[0][4][tid]+spart[1][4][tid]+spart[2][4][tid]+spart[3][4][tid];
        float4 v4; v4.x=m0; v4.y=m1; v4.z=m2; v4.w=m3;
        *reinterpret_cast<float4*>(&maps8[pix*MSTR]) = v4;
        maps8[pix*MSTR + 4] = m4;
    }

    // transposed writes: 16 reps, 4 pixels/rep, 64 threads per pixel row,
    // each thread moves 2 half2 (8 B) -> wave writes 512 B contiguous.
    #pragma unroll 4
    for (int rep=0; rep<16; ++rep){
        const int idx = rep*256 + tid;
        const int pp  = idx >> 6;          // 0..63
        const int c0  = (idx & 63) * 2;    // channel pair base
        const uint2 wv = *reinterpret_cast<const uint2*>(&tg[pp*TPAD + c0]);
        *reinterpret_cast<uint2*>(&gT[(p0+pp)*CCH + c0]) = wv;
    }
}

// ---------------------------------------------------------------------------
// Per-iteration accumulate using fp16 transposed grads + packed pixel maps.
// ---------------------------------------------------------------------------
__global__ __launch_bounds__(256)
void pnp_accum2(const float* __restrict__ pts3D,
                const float* __restrict__ fref,
                const __half2* __restrict__ gT,
                const float* __restrict__ maps8,
                const float* __restrict__ Kmat,
                const float* __restrict__ Rsrc,
                const float* __restrict__ tsrc,
                float* __restrict__ partials)
{
    const int tid = threadIdx.x;
    const int g   = tid & (TPP-1);
    const int pl  = tid >> 3;
    const int n   = blockIdx.x * PPB + pl;

    const float R00=Rsrc[0],R01=Rsrc[1],R02=Rsrc[2];
    const float R10=Rsrc[3],R11=Rsrc[4],R12=Rsrc[5];
    const float R20=Rsrc[6],R21=Rsrc[7],R22=Rsrc[8];
    const float t0=tsrc[0],t1=tsrc[1],t2=tsrc[2];
    const float K00=Kmat[0],K01=Kmat[1],K02=Kmat[2];
    const float K10=Kmat[3],K11=Kmat[4],K12=Kmat[5];
    const float K20=Kmat[6],K21=Kmat[7],K22=Kmat[8];
    const float fx=K00, fy=K11;

    const float px=pts3D[n*3+0], py=pts3D[n*3+1], pz=pts3D[n*3+2];
    const float x = R00*px + R01*py + R02*pz + t0;
    const float y = R10*px + R11*py + R12*pz + t1;
    const float z = R20*px + R21*py + R22*pz + t2;
    const float phx = K00*x + K01*y + K02*z;
    const float phy = K10*x + K11*y + K12*z;
    const float phz = K20*x + K21*y + K22*z;
    const int p2x = (int)rintf(phx/phz) - 1;
    const int p2y = (int)rintf(phy/phz) - 1;
    const bool inb = (p2x>=0) && (p2y>=0) && (p2x<IMW) && (p2y<IMH);
    const int pix = inb ? (p2y*FMW + p2x) : 0;

    float dx=0.f, dy=0.f;
    if (inb) {
        const uint4*  gp = reinterpret_cast<const uint4*>(gT + (size_t)pix*CCH + g*16);
        const float4* rp = reinterpret_cast<const float4*>(fref + (size_t)n*CCH + g*16);
        #pragma unroll
        for (int j=0;j<4;j++){
            const uint4  wv = gp[j];
            const float4 r = rp[j];
            const float2 f0 = __half22float2(*reinterpret_cast<const __half2*>(&wv.x));
            const float2 f1 = __half22float2(*reinterpret_cast<const __half2*>(&wv.y));
            const float2 f2 = __half22float2(*reinterpret_cast<const __half2*>(&wv.z));
            const float2 f3 = __half22float2(*reinterpret_cast<const __half2*>(&wv.w));
            dx = fmaf(f0.x,r.x,dx); dy = fmaf(f0.y,r.x,dy);
            dx = fmaf(f1.x,r.y,dx); dy = fmaf(f1.y,r.y,dy);
            dx = fmaf(f2.x,r.z,dx); dy = fmaf(f2.y,r.z,dy);
            dx = fmaf(f3.x,r.w,dx); dy = fmaf(f3.y,r.w,dy);
        }
    }
    #pragma unroll
    for (int d=1; d<TPP; d<<=1){
        dx += __shfl_xor(dx, d);
        dy += __shfl_xor(dy, d);
    }

    float v[NPART];
    #pragma unroll
    for (int i=0;i<NPART;i++) v[i]=0.f;
    if (inb) {
        const float4 m03 = *reinterpret_cast<const float4*>(&maps8[(size_t)pix*MSTR]);
        const float  m4  = maps8[(size_t)pix*MSTR + 4];
        const float sx  = m03.x - dx;
        const float sy  = m03.y - dy;
        const float gxx = m03.z;
        const float gxy = m03.w;
        const float gyy = m4;

        const float zi = 1.f/z;
        const float a0 = fx*zi;
        const float b0 = -fx*x*zi*zi;
        const float c1 = fy*zi;
        const float d1 = -fy*y*zi*zi;
        const float A0[6] = {a0, 0.f, b0, b0*y, a0*z - b0*x, -a0*y};
        const float A1[6] = {0.f, c1, d1, -c1*z + d1*y, -d1*x, c1*x};
        #pragma unroll
        for (int i=0;i<6;i++) v[i] = A0[i]*sx + A1[i]*sy;
        int idx=6;
        #pragma unroll
        for (int i=0;i<6;i++){
            #pragma unroll
            for (int j=i;j<6;j++){
                v[idx] = gxx*A0[i]*A0[j]
                       + gxy*(A0[i]*A1[j]+A1[i]*A0[j])
                       + gyy*A1[i]*A1[j];
                idx++;
            }
        }
    }

    __shared__ float wpart[4][NPART];
    const int wid  = tid >> 6;
    const int lane = tid & 63;
    #pragma unroll
    for (int i=0;i<NPART;i++){
        float vv = v[i];
        vv += __shfl_xor(vv, 8);
        vv += __shfl_xor(vv, 16);
        vv += __shfl_xor(vv, 32);
        if (lane==0) wpart[wid][i]=vv;
    }
    __syncthreads();
    if (tid < NPART){
        partials[blockIdx.x*NPART + tid] =
            wpart[0][tid]+wpart[1][tid]+wpart[2][tid]+wpart[3][tid];
    }
}

// ---------------------------------------------------------------------------
// Fallback accum (round-1 path) if workspace is too small for transposes.
// ---------------------------------------------------------------------------
__global__ __launch_bounds__(256)
void pnp_accum(const float* __restrict__ pts3D,
               const float* __restrict__ fref,
               const float* __restrict__ fmap,
               const float* __restrict__ gxm,
               const float* __restrict__ gym,
               const float* __restrict__ Kmat,
               const float* __restrict__ Rsrc,
               const float* __restrict__ tsrc,
               float* __restrict__ partials)
{
    const int tid = threadIdx.x;
    const int g   = tid & (TPP-1);
    const int pl  = tid >> 3;
    const int n   = blockIdx.x * PPB + pl;

    const float R00=Rsrc[0],R01=Rsrc[1],R02=Rsrc[2];
    const float R10=Rsrc[3],R11=Rsrc[4],R12=Rsrc[5];
    const float R20=Rsrc[6],R21=Rsrc[7],R22=Rsrc[8];
    const float t0=tsrc[0],t1=tsrc[1],t2=tsrc[2];
    const float K00=Kmat[0],K01=Kmat[1],K02=Kmat[2];
    const float K10=Kmat[3],K11=Kmat[4],K12=Kmat[5];
    const float K20=Kmat[6],K21=Kmat[7],K22=Kmat[8];
    const float fx=K00, fy=K11;

    const float px=pts3D[n*3+0], py=pts3D[n*3+1], pz=pts3D[n*3+2];
    const float x = R00*px + R01*py + R02*pz + t0;
    const float y = R10*px + R11*py + R12*pz + t1;
    const float z = R20*px + R21*py + R22*pz + t2;
    const float phx = K00*x + K01*y + K02*z;
    const float phy = K10*x + K11*y + K12*z;
    const float phz = K20*x + K21*y + K22*z;
    const int p2x = (int)rintf(phx/phz) - 1;
    const int p2y = (int)rintf(phy/phz) - 1;
    const bool inb = (p2x>=0) && (p2y>=0) && (p2x<IMW) && (p2y<IMH);

    float sx=0.f, sy=0.f, gxx=0.f, gxy=0.f, gyy=0.f;
    if (inb) {
        const int pix = p2y*FMW + p2x;
        const float* fm = fmap + pix;
        const float* gx = gxm  + pix;
        const float* gy = gym  + pix;
        const float4* refp =
            reinterpret_cast<const float4*>(fref + (size_t)n*CCH + g*16);
        #pragma unroll
        for (int j=0;j<4;j++){
            const float4 rv = refp[j];
            const float rarr[4] = {rv.x, rv.y, rv.z, rv.w};
            const int c0 = g*16 + j*4;
            #pragma unroll
            for (int k=0;k<4;k++){
                const int off = (c0+k)*PLANE;
                const float f = fm[off];
                const float a = gx[off];
                const float b = gy[off];
                const float e = f - rarr[k];
                sx  = fmaf(a,e,sx);
                sy  = fmaf(b,e,sy);
                gxx = fmaf(a,a,gxx);
                gxy = fmaf(a,b,gxy);
                gyy = fmaf(b,b,gyy);
            }
        }
    }
    #pragma unroll
    for (int d=1; d<TPP; d<<=1){
        sx  += __shfl_xor(sx , d);
        sy  += __shfl_xor(sy , d);
        gxx += __shfl_xor(gxx, d);
        gxy += __shfl_xor(gxy, d);
        gyy += __shfl_xor(gyy, d);
    }

    float v[NPART];
    #pragma unroll
    for (int i=0;i<NPART;i++) v[i]=0.f;
    if (inb) {
        const float zi = 1.f/z;
        const float a0 = fx*zi;
        const float b0 = -fx*x*zi*zi;
        const float c1 = fy*zi;
        const float d1 = -fy*y*zi*zi;
        const float A0[6] = {a0, 0.f, b0, b0*y, a0*z - b0*x, -a0*y};
        const float A1[6] = {0.f, c1, d1, -c1*z + d1*y, -d1*x, c1*x};
        #pragma unroll
        for (int i=0;i<6;i++) v[i] = A0[i]*sx + A1[i]*sy;
        int idx=6;
        #pragma unroll
        for (int i=0;i<6;i++){
            #pragma unroll
            for (int j=i;j<6;j++){
                v[idx] = gxx*A0[i]*A0[j]
                       + gxy*(A0[i]*A1[j]+A1[i]*A0[j])
                       + gyy*A1[i]*A1[j];
                idx++;
            }
        }
    }

    __shared__ float wpart[4][NPART];
    const int wid  = tid >> 6;
    const int lane = tid & 63;
    #pragma unroll
    for (int i=0;i<NPART;i++){
        float vv = v[i];
        vv += __shfl_xor(vv, 8);
        vv += __shfl_xor(vv, 16);
        vv += __shfl_xor(vv, 32);
        if (lane==0) wpart[wid][i]=vv;
    }
    __syncthreads();
    if (tid < NPART){
        partials[blockIdx.x*NPART + tid] =
            wpart[0][tid]+wpart[1][tid]+wpart[2][tid]+wpart[3][tid];
    }
}

// ---------------------------------------------------------------------------
// Parallel-reduce partials, damp, solve 6x6, so3exp, update R,t.
// ---------------------------------------------------------------------------
__global__ void pnp_solve(const float* __restrict__ partials,
                          const float* __restrict__ Rsrc,
                          const float* __restrict__ tsrc,
                          float* __restrict__ RtWs,
                          float* __restrict__ outp)
{
    __shared__ double red[NPART*8];
    const int t = threadIdx.x;
    if (t < NPART*8){
        const int col = t % NPART;
        const int grp = t / NPART;
        double s0 = 0.0, s1 = 0.0;
        for (int p = grp; p < NBLK; p += 16){
            s0 += (double)partials[p*NPART + col];
            s1 += (double)partials[(p+8)*NPART + col];
        }
        red[col*8 + grp] = s0 + s1;
    }
    __syncthreads();
    if (t < NPART){
        double s = 0.0;
        #pragma unroll
        for (int k=0;k<8;k++) s += red[t*8 + k];
        red[t*8] = s;
    }
    __syncthreads();
    if (t==0){
        double gv[6]; double H[6][6];
        for (int i=0;i<6;i++) gv[i]=red[i*8];
        int idx=6;
        for (int i=0;i<6;i++)
            for (int j=i;j<6;j++){
                H[i][j]=red[idx*8]; H[j][i]=red[idx*8]; idx++;
            }
        for (int i=0;i<6;i++) H[i][i] += 0.01*(H[i][i] + 1e-9);

        double M[6][6], b[6];
        for (int i=0;i<6;i++){ b[i]=gv[i]; for (int j=0;j<6;j++) M[i][j]=H[i][j]; }
        for (int c=0;c<6;c++){
            int piv=c; double mx=fabs(M[c][c]);
            for (int r=c+1;r<6;r++){ double av=fabs(M[r][c]); if (av>mx){mx=av;piv=r;} }
            if (piv!=c){
                for (int j=c;j<6;j++){ double tmp=M[c][j]; M[c][j]=M[piv][j]; M[piv][j]=tmp; }
                double tb=b[c]; b[c]=b[piv]; b[piv]=tb;
            }
            const double inv = 1.0/M[c][c];
            for (int r=c+1;r<6;r++){
                const double f = M[r][c]*inv;
                for (int j=c;j<6;j++) M[r][j] -= f*M[c][j];
                b[r] -= f*b[c];
            }
        }
        double xs[6];
        for (int r=5;r>=0;r--){
            double s2=b[r];
            for (int j=r+1;j<6;j++) s2 -= M[r][j]*xs[j];
            xs[r]=s2/M[r][r];
        }
        double delta[6];
        for (int i=0;i<6;i++) delta[i] = -xs[i];

        const double wx=delta[3], wy=delta[4], wz=delta[5];
        const double th = sqrt(wx*wx+wy*wy+wz*wz + 1e-24);
        const double Ath = sin(th)/th;
        const double Bth = (1.0-cos(th))/(th*th);
        const double W[3][3] = {{0.0,-wz,wy},{wz,0.0,-wx},{-wy,wx,0.0}};
        double W2[3][3];
        for (int i=0;i<3;i++) for (int j=0;j<3;j++){
            double s2=0; for (int k2=0;k2<3;k2++) s2 += W[i][k2]*W[k2][j];
            W2[i][j]=s2;
        }
        double dR[3][3];
        for (int i=0;i<3;i++) for (int j=0;j<3;j++)
            dR[i][j] = (i==j?1.0:0.0) + Ath*W[i][j] + Bth*W2[i][j];

        double Ro[3][3];
        for (int i=0;i<3;i++) for (int j=0;j<3;j++) Ro[i][j]=(double)Rsrc[i*3+j];
        const double to0=(double)tsrc[0], to1=(double)tsrc[1], to2=(double)tsrc[2];

        double Rn[3][3], tn[3];
        for (int i=0;i<3;i++){
            for (int j=0;j<3;j++){
                double s2=0; for (int k2=0;k2<3;k2++) s2 += dR[i][k2]*Ro[k2][j];
                Rn[i][j]=s2;
            }
            tn[i] = dR[i][0]*to0 + dR[i][1]*to1 + dR[i][2]*to2 + delta[i];
        }
        for (int i=0;i<3;i++) for (int j=0;j<3;j++){
            RtWs[i*3+j] = (float)Rn[i][j];
            outp[i*3+j] = (float)Rn[i][j];
        }
        for (int i=0;i<3;i++){ RtWs[9+i]=(float)tn[i]; outp[9+i]=(float)tn[i]; }
    }
}

extern "C" void kernel_launch(void* const* d_in, const int* in_sizes, int n_in,
                              void* d_out, int out_size, void* d_ws, size_t ws_size,
                              hipStream_t stream)
{
    const float* pts   = (const float*)d_in[0];
    const float* fref  = (const float*)d_in[1];
    const float* fmap  = (const float*)d_in[2];
    const float* gxm   = (const float*)d_in[3];
    const float* gym   = (const float*)d_in[4];
    const float* Kmat  = (const float*)d_in[5];
    const float* Rin   = (const float*)d_in[6];
    const float* tin   = (const float*)d_in[7];
    float* outp = (float*)d_out;

    // workspace layout: [partials][RtWs][maps8(8*PLANE f32)][gT(PLANE*128 half2)]
    float* partials = (float*)d_ws;
    float* RtWs  = partials + NBLK*NPART;
    float* maps8 = RtWs + 12;
    __half2* gT  = reinterpret_cast<__half2*>(maps8 + (size_t)MSTR*PLANE);
    const size_t needed_bytes = ((size_t)NBLK*NPART + 12 + (size_t)MSTR*PLANE) * 4
                                + (size_t)PLANE*CCH * sizeof(__half2);

    const bool fast = (ws_size >= needed_bytes);
    if (fast){
        pnp_prep<<<PLANE/64, 256, 0, stream>>>(fmap, gxm, gym, gT, maps8);
    }

    const float* Rs = Rin;
    const float* ts = tin;
    for (int it=0; it<5; ++it){
        if (fast){
            pnp_accum2<<<NBLK, 256, 0, stream>>>(pts, fref, gT, maps8,
                                                 Kmat, Rs, ts, partials);
        } else {
            pnp_accum<<<NBLK, 256, 0, stream>>>(pts, fref, fmap, gxm, gym,
                                                Kmat, Rs, ts, partials);
        }
        pnp_solve<<<1, 256, 0, stream>>>(partials, Rs, ts, RtWs, outp);
        Rs = RtWs; ts = RtWs + 9;
    }
}